// Round 10
// baseline (97.376 us; speedup 1.0000x reference)
//
#include <hip/hip_runtime.h>
#include <hip/hip_fp16.h>

// DeformableConv2DLayer: B=4, Cin=64, H=W=128, Cout=64, 3x3, s=1, p=1, DG=1
#define B_   4
#define CIN  64
#define HH   128
#define WW   128
#define COUT 64
#define HW   (HH * WW)          // 16384
#define KK   9

// LDS window geometry: 6 rows (ho0-2..ho0+3) x 72 cols (ch*64-4 .. +67)
#define WROWS 6
#define WCOLS 72
#define ROWSTRIDE (WCOLS * 128)   // 9216 B per window row

typedef float    f32x4 __attribute__((ext_vector_type(4)));
typedef _Float16 f16x8 __attribute__((ext_vector_type(8)));

union U4 {
    uint4     q;
    uint32_t  u[4];
    __half2   h2[4];
    f16x8     v;
};

#define MFMA16(a, b, c) __builtin_amdgcn_mfma_f32_16x16x32_f16((a).v, (b).v, (c), 0, 0, 0)

// ---------------------------------------------------------------------------
// Prep kernel: weight packing only.
// MFMA B-frag order: frag (t, nt); lane l holds o = nt*16+(l&15),
// K-elem r = t*32+(l>>4)*8+j, with r = tap*64 + c -> tap = r>>6, c = r&63.
// ---------------------------------------------------------------------------
__global__ __launch_bounds__(256)
void prep_kernel(const float* __restrict__ w,
                 const float* __restrict__ ow,
                 __half* __restrict__ wpack,
                 __half* __restrict__ wop) {
    int i = blockIdx.x * 256 + threadIdx.x;        // 0..55295
    if (i < 36864) {                               // main weights
        int j = i & 7, l = (i >> 3) & 63, s = i >> 9;  // s = t*4+nt
        int t = s >> 2;
        int rr = t * 32 + ((l >> 4) << 3) + j;
        int c = rr & 63, k = rr >> 6;
        int o = (s & 3) * 16 + (l & 15);
        wpack[i] = __float2half(w[(o * CIN + c) * KK + k]);
    } else {                                       // offset weights
        int i2 = i - 36864;                        // < 18432
        int j = i2 & 7, l = (i2 >> 3) & 63, s = i2 >> 9; // s = t*2+nt
        int t = s >> 1;
        int rr = t * 32 + ((l >> 4) << 3) + j;
        int c = rr & 63, k = rr >> 6;
        int o = (s & 1) * 16 + (l & 15);
        wop[i2] = __float2half((o < 27) ? ow[(o * CIN + c) * KK + k] : 0.f);
    }
}

// ---------------------------------------------------------------------------
// Fused DCN kernel. Block = 256 thr = 4 waves = 2 output rows x 64 cols
// (+4-col margin in the staged window). LDS: 6 rows x 72 cols x 64ch fp16
// (54 KB, XOR-swizzled) + packed per-pixel offset results (9 KB) = 64.5 KB
// -> 2 blocks/CU (two barrier domains overlap staging with compute).
// Stage converts fp32 NCHW -> fp16 NHWC-in-LDS directly. Phase 1 = offset
// conv via MFMA -> packed (dy,dx,mk) f16x4 per (px,tap). Phase 2 = bilinear
// from LDS + 64x576 MFMA; out-of-window taps (|off|>=1, ~4sigma) take a
// wave-uniform global-gather fallback, correct for any offset.
// ---------------------------------------------------------------------------
__global__ __launch_bounds__(256, 2)
void dcn_fused_kernel(const float* __restrict__ x,
                      const __half* __restrict__ wop,
                      const float* __restrict__ ob,
                      const __half* __restrict__ wpack,
                      const float* __restrict__ bias,
                      float* __restrict__ out) {
    int bid0 = blockIdx.x;
    int bid  = (bid0 & 7) * 64 + (bid0 >> 3);   // bijective XCD swizzle (512%8==0)
    int ch = bid & 1, rp = (bid >> 1) & 63, b = bid >> 7;
    int ho0 = rp * 2;
    int wstart = ch * 64 - 4;
    int tid = threadIdx.x;
    int w = tid >> 6, l = tid & 63;
    int p = l & 15, grp = l >> 4, grp16 = grp << 4;
    int r = w >> 1, q = w & 1;                  // output row (0/1), col quadrant
    int ho = ho0 + r;
    int wo0 = ch * 64 + q * 32;                 // wave's 32-px segment

    __shared__ __align__(16) char xs[WROWS * ROWSTRIDE];   // 55296 B
    __shared__ __half lompH[4][32][9][4];                  // (dy,dx,mk,pad) 9216 B

    const float* xbF = x + (size_t)b * CIN * HW;   // fp32 NCHW batch base

    // ------- stage window from NCHW fp32: convert + swizzled LDS write -----
#pragma unroll
    for (int it = 0; it < 14; ++it) {
        int idx = it * 256 + tid;               // 0..3455 16B slots
        if (idx < WROWS * WCOLS * 8) {
            int wc = idx % WCOLS;
            int tmp = idx / WCOLS;
            int cg = tmp & 7, rr = tmp >> 3;
            int srow = min(max(ho0 - 2 + rr, 0), HH - 1);
            int scol = min(max(wstart + wc, 0), WW - 1);
            const float* xp = xbF + (size_t)(cg * 8) * HW + srow * WW + scol;
            uint32_t u[4];
#pragma unroll
            for (int j = 0; j < 4; ++j) {
                __half2 h = __floats2half2_rn(xp[(size_t)(2 * j) * HW],
                                              xp[(size_t)(2 * j + 1) * HW]);
                u[j] = *(uint32_t*)&h;
            }
            *(uint4*)(xs + ((rr * ROWSTRIDE + (wc << 7) + (cg << 4)) ^ ((wc & 7) << 4)))
                = *(const uint4*)u;
        }
    }
    __syncthreads();

    // ---------------- Phase 1: offset/mask conv from LDS -------------------
    {
        const uint4* wpo = (const uint4*)wop + l;
        int aad[2][9], asw[2][9];
        uint32_t avm[2][9];
#pragma unroll
        for (int m = 0; m < 2; ++m)
#pragma unroll
        for (int k = 0; k < 9; ++k) {
            int ki = k / 3, kj = k % 3;
            int hh = ho + ki - 1;
            int cr = wo0 + m * 16 + p + kj - 1;
            bool v = ((unsigned)hh < (unsigned)HH) && ((unsigned)cr < (unsigned)WW);
            int slot = r + ki + 1;              // in [1,4] of 6-row window
            int cc = min(max(cr, 0), WW - 1);
            int wcx = cc - wstart;              // in [0,71]
            aad[m][k] = slot * ROWSTRIDE + (wcx << 7) + grp16;
            asw[m][k] = (wcx & 7) << 4;
            avm[m][k] = v ? 0xffffffffu : 0u;
        }
        f32x4 oacc[2][2] = {};
#pragma unroll
        for (int t = 0; t < 18; ++t) {
            int k = t >> 1, half = t & 1;
            U4 a0, a1;
            a0.q = *(const uint4*)(xs + ((aad[0][k] + (half << 6)) ^ asw[0][k]));
            a1.q = *(const uint4*)(xs + ((aad[1][k] + (half << 6)) ^ asw[1][k]));
#pragma unroll
            for (int i = 0; i < 4; ++i) { a0.u[i] &= avm[0][k]; a1.u[i] &= avm[1][k]; }
            U4 b0, b1;
            b0.q = wpo[(t * 2 + 0) * 64];
            b1.q = wpo[(t * 2 + 1) * 64];
            oacc[0][0] = MFMA16(a0, b0, oacc[0][0]);
            oacc[0][1] = MFMA16(a0, b1, oacc[0][1]);
            oacc[1][0] = MFMA16(a1, b0, oacc[1][0]);
            oacc[1][1] = MFMA16(a1, b1, oacc[1][1]);
        }
        // D: col = lane&15 (= oc in tile), row = grp*4+i (= pixel in strip).
        // oc -> (field = oc/9: 0=dy 1=dx 2=mk, tap = oc%9), packed per px.
#pragma unroll
        for (int m = 0; m < 2; ++m)
#pragma unroll
        for (int nt = 0; nt < 2; ++nt) {
            int oc = nt * 16 + (l & 15);
            if (oc < 27) {
                float bv = ob[oc];
                int f = oc / 9, kk = oc - f * 9;
#pragma unroll
                for (int i = 0; i < 4; ++i) {
                    float vv = oacc[m][nt][i] + bv;
                    if (f == 2) vv = 1.f / (1.f + __expf(-vv));   // sigmoid mask
                    lompH[w][m * 16 + grp * 4 + i][kk][f] = __float2half(vv);
                }
            }
        }
    }
    // lompH is wave-private: same-wave LDS RAW ordered by lgkmcnt (compiler)

    // ---------------- Phase 2: deformable conv from LDS --------------------
    f32x4 acc[2][4] = {};
    const uint4* wpm = (const uint4*)wpack + l;

#pragma unroll
    for (int k = 0; k < 9; ++k) {
        int ch0[2], ch1[2], cw0[2], cw1[2];
        __half2 hwA[2], hwB[2], hwC[2], hwD[2];
        int okall = 1;
#pragma unroll
        for (int m = 0; m < 2; ++m) {
            int px = m * 16 + p;
            uint2 lv = *(const uint2*)&lompH[w][px][k][0];   // single b64 read
            __half2 d01 = *(__half2*)&lv.x;                  // (dy, dx)
            __half2 d2x = *(__half2*)&lv.y;                  // (mk, pad)
            float dy = __half2float(__low2half(d01));
            float dx = __half2float(__high2half(d01));
            float mk = __half2float(__low2half(d2x));
            float hf = (float)(ho - 1 + k / 3) + dy;
            float wf = (float)(wo0 + px - 1 + k % 3) + dx;
            float h0f = floorf(hf), w0f = floorf(wf);
            float lh = hf - h0f, lw = wf - w0f;
            int h0 = (int)h0f, w0i = (int)w0f;
            int h1 = h0 + 1, w1i = w0i + 1;
            bool vh0 = (unsigned)h0 < (unsigned)HH, vh1 = (unsigned)h1 < (unsigned)HH;
            bool vw0 = (unsigned)w0i < (unsigned)WW, vw1 = (unsigned)w1i < (unsigned)WW;
            int c0 = min(max(h0, 0), HH - 1), c1 = min(max(h1, 0), HH - 1);
            int d0 = min(max(w0i, 0), WW - 1), d1 = min(max(w1i, 0), WW - 1);
            ch0[m] = c0; ch1[m] = c1; cw0[m] = d0; cw1[m] = d1;
            float fA = (vh0 && vw0) ? (1.f - lh) * (1.f - lw) * mk : 0.f;
            float fB = (vh0 && vw1) ? (1.f - lh) * lw * mk : 0.f;
            float fC = (vh1 && vw0) ? lh * (1.f - lw) * mk : 0.f;
            float fD = (vh1 && vw1) ? lh * lw * mk : 0.f;
            hwA[m] = __float2half2_rn(fA); hwB[m] = __float2half2_rn(fB);
            hwC[m] = __float2half2_rn(fC); hwD[m] = __float2half2_rn(fD);
            int s0 = c0 + 2 - ho0, s1 = c1 + 2 - ho0;
            int e0 = d0 - wstart,  e1 = d1 - wstart;
            okall &= (int)((unsigned)s0 <= 5u) & (int)((unsigned)s1 <= 5u)
                   & (int)((unsigned)e0 <= 71u) & (int)((unsigned)e1 <= 71u);
        }
        int okw = __all(okall);

#pragma unroll
        for (int half = 0; half < 2; ++half) {
            int t = 2 * k + half;
            int hb = (half << 6) + grp16;
            U4 bf0, bf1, bf2, bf3;
            bf0.q = wpm[(t * 4 + 0) * 64];
            bf1.q = wpm[(t * 4 + 1) * 64];
            bf2.q = wpm[(t * 4 + 2) * 64];
            bf3.q = wpm[(t * 4 + 3) * 64];
            U4 a[2];
            if (okw) {
#pragma unroll
                for (int m = 0; m < 2; ++m) {
                    int s0 = ch0[m] + 2 - ho0, s1 = ch1[m] + 2 - ho0;
                    int e0 = cw0[m] - wstart,  e1 = cw1[m] - wstart;
                    U4 u0, u1, u2, u3;
                    u0.q = *(const uint4*)(xs + ((s0 * ROWSTRIDE + (e0 << 7) + hb) ^ ((e0 & 7) << 4)));
                    u1.q = *(const uint4*)(xs + ((s0 * ROWSTRIDE + (e1 << 7) + hb) ^ ((e1 & 7) << 4)));
                    u2.q = *(const uint4*)(xs + ((s1 * ROWSTRIDE + (e0 << 7) + hb) ^ ((e0 & 7) << 4)));
                    u3.q = *(const uint4*)(xs + ((s1 * ROWSTRIDE + (e1 << 7) + hb) ^ ((e1 & 7) << 4)));
#pragma unroll
                    for (int i = 0; i < 4; ++i)
                        a[m].h2[i] = __hfma2(hwD[m], u3.h2[i],
                                     __hfma2(hwC[m], u2.h2[i],
                                     __hfma2(hwB[m], u1.h2[i],
                                     __hmul2(hwA[m], u0.h2[i]))));
                }
            } else {
                // rare fallback: gather 8 channels per corner from fp32 NCHW
                const float* cbase = xbF + (size_t)(32 * half + grp * 8) * HW;
#pragma unroll
                for (int m = 0; m < 2; ++m) {
                    U4 u0, u1, u2, u3;
#pragma unroll
                    for (int j = 0; j < 4; ++j) {
                        const float* p0 = cbase + (size_t)(2 * j) * HW;
                        const float* p1 = cbase + (size_t)(2 * j + 1) * HW;
                        int i00 = ch0[m] * WW + cw0[m], i01 = ch0[m] * WW + cw1[m];
                        int i10 = ch1[m] * WW + cw0[m], i11 = ch1[m] * WW + cw1[m];
                        __half2 h;
                        h = __floats2half2_rn(p0[i00], p1[i00]); u0.u[j] = *(uint32_t*)&h;
                        h = __floats2half2_rn(p0[i01], p1[i01]); u1.u[j] = *(uint32_t*)&h;
                        h = __floats2half2_rn(p0[i10], p1[i10]); u2.u[j] = *(uint32_t*)&h;
                        h = __floats2half2_rn(p0[i11], p1[i11]); u3.u[j] = *(uint32_t*)&h;
                    }
#pragma unroll
                    for (int i = 0; i < 4; ++i)
                        a[m].h2[i] = __hfma2(hwD[m], u3.h2[i],
                                     __hfma2(hwC[m], u2.h2[i],
                                     __hfma2(hwB[m], u1.h2[i],
                                     __hmul2(hwA[m], u0.h2[i]))));
                }
            }
            acc[0][0] = MFMA16(a[0], bf0, acc[0][0]);
            acc[0][1] = MFMA16(a[0], bf1, acc[0][1]);
            acc[0][2] = MFMA16(a[0], bf2, acc[0][2]);
            acc[0][3] = MFMA16(a[0], bf3, acc[0][3]);
            acc[1][0] = MFMA16(a[1], bf0, acc[1][0]);
            acc[1][1] = MFMA16(a[1], bf1, acc[1][1]);
            acc[1][2] = MFMA16(a[1], bf2, acc[1][2]);
            acc[1][3] = MFMA16(a[1], bf3, acc[1][3]);
        }
    }

    // ---------------- Epilogue: D col = cout-in-tile, row = pixel ----------
#pragma unroll
    for (int m = 0; m < 2; ++m)
#pragma unroll
    for (int nt = 0; nt < 4; ++nt) {
        int oc = nt * 16 + (l & 15);
        float bv = bias[oc];
        f32x4 s;
#pragma unroll
        for (int i = 0; i < 4; ++i) s[i] = acc[m][nt][i] + bv;
        *(f32x4*)(out + ((size_t)(b * COUT + oc)) * HW + ho * WW + wo0 + m * 16 + grp * 4) = s;
    }
}

// ---------------------------------------------------------------------------
extern "C" void kernel_launch(void* const* d_in, const int* in_sizes, int n_in,
                              void* d_out, int out_size, void* d_ws, size_t ws_size,
                              hipStream_t stream) {
    const float* x    = (const float*)d_in[0];
    const float* wgt  = (const float*)d_in[1];
    const float* bias = (const float*)d_in[2];
    const float* ow   = (const float*)d_in[3];
    const float* ob   = (const float*)d_in[4];
    float* out = (float*)d_out;

    // workspace: wpack 73728B | wop 36864B
    char* ws = (char*)d_ws;
    __half* wpack = (__half*)ws;
    __half* wop   = (__half*)(ws + 73728);

    prep_kernel<<<216, 256, 0, stream>>>(wgt, ow, wpack, wop);
    dcn_fused_kernel<<<B_ * HH, 256, 0, stream>>>(x, wop, ob, wpack, bias, out);
}